// Round 3
// baseline (1041.613 us; speedup 1.0000x reference)
//
#include <hip/hip_runtime.h>
#include <hip/hip_bf16.h>

typedef __attribute__((ext_vector_type(8))) short short8;
typedef __attribute__((ext_vector_type(4))) short short4v;
typedef __attribute__((ext_vector_type(4))) float f32x4;

#define SEQ    2048
#define DM     1024
#define NH     16
#define DH     64
#define NBATCH 4
#define MTOK   (NBATCH * SEQ)                       // 8192 tokens
#define SEG    ((size_t)NBATCH * NH * SEQ * DH)     // 8388608 elems per Q/K/V buffer

static __device__ __forceinline__ unsigned short f2bf(float f) {
  __hip_bfloat16 h = __float2bfloat16(f);
  union { __hip_bfloat16 h; unsigned short u; } cv;
  cv.h = h;
  return cv.u;
}

// ---------------------------------------------------------------------------
// GEMM: C[M,N] = A[M,K] @ B[K,N], fp32 accum, MFMA on bf16-converted tiles.
// 128x128 tile / block of 256 threads (4 waves in 2x2), BK=32.
// MODE 0: A fp32 (x), B fp32 (W_qkv); scatter epilogue into Q/K/V bf16 bufs.
// MODE 1: A bf16 (ctx), B fp32 (W_o); plain row-major FP32 output.
// ---------------------------------------------------------------------------
template <int MODE>
__global__ __launch_bounds__(256) void gemm_kernel(
    const void* __restrict__ Av, const float* __restrict__ B,
    unsigned short* __restrict__ out0, unsigned short* __restrict__ out1,
    unsigned short* __restrict__ out2, float* __restrict__ outf,
    int M, int N, int K) {
  __shared__ unsigned short As[128][32];  // As[m][k] (bf16)
  __shared__ unsigned short Bs[128][32];  // Bs[n][k] (bf16, B transposed)

  const int tid = threadIdx.x;
  const int wave = tid >> 6;
  const int lane = tid & 63;
  const int quad = lane >> 4;
  const int lc = lane & 15;
  const int wr = wave >> 1;  // wave row (0/1) -> 64-row half
  const int wc = wave & 1;   // wave col (0/1) -> 64-col half
  const int m0 = blockIdx.y * 128;
  const int n0 = blockIdx.x * 128;

  f32x4 acc[4][4];
#pragma unroll
  for (int i = 0; i < 4; i++)
#pragma unroll
    for (int j = 0; j < 4; j++) acc[i][j] = (f32x4){0.f, 0.f, 0.f, 0.f};

  for (int k0 = 0; k0 < K; k0 += 32) {
    // ---- Stage A tile (128 x 32) ----
    if (MODE == 0) {
      // A is fp32: 4096 floats = 1024 float4 chunks, 4 per thread.
      const float* A = (const float*)Av;
#pragma unroll
      for (int i = 0; i < 4; i++) {
        int chunk = tid + i * 256;
        int r = chunk >> 3;          // 8 float4 per 32-col row
        int c4 = (chunk & 7) * 4;
        f32x4 v = *(const f32x4*)&A[(size_t)(m0 + r) * K + k0 + c4];
        short4v s;
#pragma unroll
        for (int j = 0; j < 4; j++) s[j] = (short)f2bf(v[j]);
        *(short4v*)&As[r][c4] = s;
      }
    } else {
      // A is bf16: 512 short8 chunks, 2 per thread.
      const unsigned short* A = (const unsigned short*)Av;
#pragma unroll
      for (int i = 0; i < 2; i++) {
        int chunk = tid + i * 256;
        int r = chunk >> 2;
        int c8 = (chunk & 3) * 8;
        *(short8*)&As[r][c8] =
            *(const short8*)&A[(size_t)(m0 + r) * K + k0 + c8];
      }
    }
    // ---- Stage B tile transposed (rows k0..k0+31, cols n0..n0+127), fp32 ----
#pragma unroll
    for (int i = 0; i < 4; i++) {
      int chunk = tid + i * 256;
      int kr = chunk >> 5;           // 32 float4 per 128-col row
      int c4 = (chunk & 31) * 4;
      f32x4 v = *(const f32x4*)&B[(size_t)(k0 + kr) * N + n0 + c4];
#pragma unroll
      for (int j = 0; j < 4; j++) Bs[c4 + j][kr] = f2bf(v[j]);
    }
    __syncthreads();

    short8 aA[4], bB[4];
#pragma unroll
    for (int mt = 0; mt < 4; mt++)
      aA[mt] = *(const short8*)&As[wr * 64 + mt * 16 + lc][quad * 8];
#pragma unroll
    for (int nt = 0; nt < 4; nt++)
      bB[nt] = *(const short8*)&Bs[wc * 64 + nt * 16 + lc][quad * 8];
#pragma unroll
    for (int mt = 0; mt < 4; mt++)
#pragma unroll
      for (int nt = 0; nt < 4; nt++)
        acc[mt][nt] = __builtin_amdgcn_mfma_f32_16x16x32_bf16(
            aA[mt], bB[nt], acc[mt][nt], 0, 0, 0);
    __syncthreads();
  }

  // Epilogue: C/D layout col=lane&15, row=quad*4+reg.
#pragma unroll
  for (int mt = 0; mt < 4; mt++)
#pragma unroll
    for (int nt = 0; nt < 4; nt++)
#pragma unroll
      for (int r = 0; r < 4; r++) {
        int row = m0 + wr * 64 + mt * 16 + quad * 4 + r;
        int col = n0 + wc * 64 + nt * 16 + lc;
        float v = acc[mt][nt][r];
        if (MODE == 0) {
          int c = col >> 10;       // 0=Q 1=K 2=V
          int rem = col & 1023;
          int h = rem >> 6;
          int dd = rem & 63;
          int b = row >> 11;
          int tt = row & 2047;
          unsigned short* dst = (c == 0) ? out0 : ((c == 1) ? out1 : out2);
          dst[(((size_t)(b * NH + h) * SEQ + tt) << 6) + dd] = f2bf(v);
        } else {
          outf[(size_t)row * N + col] = v;   // fp32 final output
        }
      }
}

// ---------------------------------------------------------------------------
// Flash attention over head-major Q/K/V [BH=64][T=2048][64] bf16.
// Block = 256 threads = 4 waves; each wave owns 16 q-rows (64 rows/block).
// Iterate 32-key tiles with online softmax; P routed through LDS into
// MFMA A-layout; PV via 16x16x32 MFMA over the 32-key chunk.
// ---------------------------------------------------------------------------
__global__ __launch_bounds__(256) void attn_kernel(
    const unsigned short* __restrict__ Q, const unsigned short* __restrict__ K,
    const unsigned short* __restrict__ V, unsigned short* __restrict__ ctx) {
  __shared__ unsigned short Ks[32][64];      // Ks[key][d]
  __shared__ unsigned short Vst[64][32];     // Vst[d][key]  (V transposed)
  __shared__ unsigned short Ps[4][16][32];   // per-wave P[qrow][key]

  const int tid = threadIdx.x;
  const int wave = tid >> 6;
  const int lane = tid & 63;
  const int quad = lane >> 4;
  const int lc = lane & 15;
  const int bh = blockIdx.y;                  // 0..63
  const int q0 = blockIdx.x * 64 + wave * 16; // this wave's first q-row
  const size_t base = (size_t)bh * SEQ * DH;

  // Q fragments (A-layout): row = q0+lc, k = step*32 + quad*8 + j
  const short8 aQ0 = *(const short8*)&Q[base + (size_t)(q0 + lc) * DH + quad * 8];
  const short8 aQ1 =
      *(const short8*)&Q[base + (size_t)(q0 + lc) * DH + 32 + quad * 8];

  float m_i[4], l_i[4];
  f32x4 o[4];
#pragma unroll
  for (int r = 0; r < 4; r++) {
    m_i[r] = -INFINITY;
    l_i[r] = 0.f;
  }
#pragma unroll
  for (int nt = 0; nt < 4; nt++) o[nt] = (f32x4){0.f, 0.f, 0.f, 0.f};

  for (int kt = 0; kt < SEQ / 32; kt++) {
    // Cooperative staging: 32x64 K tile (coalesced) + V tile transposed.
    {
      int row = tid >> 3;
      int c8 = (tid & 7) * 8;
      *(short8*)&Ks[row][c8] =
          *(const short8*)&K[base + (size_t)(kt * 32 + row) * DH + c8];
      short8 v = *(const short8*)&V[base + (size_t)(kt * 32 + row) * DH + c8];
#pragma unroll
      for (int j = 0; j < 8; j++) Vst[c8 + j][row] = (unsigned short)v[j];
    }
    __syncthreads();

    // S = Q @ K^T for two 16-key column tiles (B-layout: n=key, k=d).
    const short8 bK00 = *(const short8*)&Ks[lc][quad * 8];
    const short8 bK01 = *(const short8*)&Ks[lc][32 + quad * 8];
    const short8 bK10 = *(const short8*)&Ks[16 + lc][quad * 8];
    const short8 bK11 = *(const short8*)&Ks[16 + lc][32 + quad * 8];
    const f32x4 z = (f32x4){0.f, 0.f, 0.f, 0.f};
    f32x4 s0 = __builtin_amdgcn_mfma_f32_16x16x32_bf16(aQ0, bK00, z, 0, 0, 0);
    s0 = __builtin_amdgcn_mfma_f32_16x16x32_bf16(aQ1, bK01, s0, 0, 0, 0);
    f32x4 s1 = __builtin_amdgcn_mfma_f32_16x16x32_bf16(aQ0, bK10, z, 0, 0, 0);
    s1 = __builtin_amdgcn_mfma_f32_16x16x32_bf16(aQ1, bK11, s1, 0, 0, 0);

    float alpha[4];
#pragma unroll
    for (int r = 0; r < 4; r++) {
      float v0 = s0[r] * 0.125f;  // 1/sqrt(64)
      float v1 = s1[r] * 0.125f;
      float mx = fmaxf(v0, v1);
#pragma unroll
      for (int off = 1; off < 16; off <<= 1) mx = fmaxf(mx, __shfl_xor(mx, off));
      float mnew = fmaxf(m_i[r], mx);
      alpha[r] = __expf(m_i[r] - mnew);  // first iter: exp(-inf)=0
      m_i[r] = mnew;
      float p0 = __expf(v0 - mnew);
      float p1 = __expf(v1 - mnew);
      float ps = p0 + p1;
#pragma unroll
      for (int off = 1; off < 16; off <<= 1) ps += __shfl_xor(ps, off);
      l_i[r] = l_i[r] * alpha[r] + ps;
      Ps[wave][quad * 4 + r][lc] = f2bf(p0);
      Ps[wave][quad * 4 + r][16 + lc] = f2bf(p1);
    }
#pragma unroll
    for (int nt = 0; nt < 4; nt++)
#pragma unroll
      for (int r = 0; r < 4; r++) o[nt][r] *= alpha[r];
    __syncthreads();

    // PV: A-layout P[m=lc][k=quad*8+j]; B-layout V[k=key][n=d].
    const short8 pA = *(const short8*)&Ps[wave][lc][quad * 8];
#pragma unroll
    for (int nt = 0; nt < 4; nt++) {
      const short8 bV = *(const short8*)&Vst[nt * 16 + lc][quad * 8];
      o[nt] = __builtin_amdgcn_mfma_f32_16x16x32_bf16(pA, bV, o[nt], 0, 0, 0);
    }
    __syncthreads();
  }

  // Normalize and store context as [B][T][H*64] (token-major) for the
  // output projection GEMM.
  const int b = bh >> 4;
  const int h = bh & 15;
#pragma unroll
  for (int nt = 0; nt < 4; nt++)
#pragma unroll
    for (int r = 0; r < 4; r++) {
      int trow = q0 + quad * 4 + r;
      int d = nt * 16 + lc;
      float v = o[nt][r] / l_i[r];
      ctx[(size_t)(b * SEQ + trow) * DM + h * DH + d] = f2bf(v);
    }
}

extern "C" void kernel_launch(void* const* d_in, const int* in_sizes, int n_in,
                              void* d_out, int out_size, void* d_ws,
                              size_t ws_size, hipStream_t stream) {
  const float* x = (const float*)d_in[0];     // [4,2048,1024] fp32
  const float* Wqkv = (const float*)d_in[1];  // [1024,3072]   fp32
  const float* Wo = (const float*)d_in[2];    // [1024,1024]   fp32
  float* out = (float*)d_out;                 // [4,2048,1024] fp32
  unsigned short* ws = (unsigned short*)d_ws;

  unsigned short* Qb = ws;            // [4,16,2048,64] bf16
  unsigned short* Kb = ws + SEG;
  unsigned short* Vb = ws + 2 * SEG;
  unsigned short* Ctx = ws + 3 * SEG; // [8192,1024] bf16

  // 1) qkv = x @ W_qkv, scattered into head-major Q/K/V.
  gemm_kernel<0><<<dim3(3 * DM / 128, MTOK / 128), 256, 0, stream>>>(
      (const void*)x, Wqkv, Qb, Kb, Vb, nullptr, MTOK, 3 * DM, DM);
  // 2) attention per (b,h), 64 q-rows per block.
  attn_kernel<<<dim3(SEQ / 64, NBATCH * NH), 256, 0, stream>>>(Qb, Kb, Vb, Ctx);
  // 3) out = ctx @ W_o  (fp32 output).
  gemm_kernel<1><<<dim3(DM / 128, MTOK / 128), 256, 0, stream>>>(
      (const void*)Ctx, Wo, nullptr, nullptr, nullptr, out, MTOK, DM, DM);
}

// Round 4
// 365.270 us; speedup vs baseline: 2.8516x; 2.8516x over previous
//
#include <hip/hip_runtime.h>
#include <hip/hip_bf16.h>

typedef __attribute__((ext_vector_type(8))) short short8;
typedef __attribute__((ext_vector_type(4))) short short4v;
typedef __attribute__((ext_vector_type(4))) float f32x4;

#define SEQ    2048
#define DM     1024
#define NH     16
#define DH     64
#define NBATCH 4
#define MTOK   (NBATCH * SEQ)                       // 8192 tokens
#define SEG    ((size_t)NBATCH * NH * SEQ * DH)     // 8388608 elems per Q/K/V buffer
// Q pre-scaled by 1/sqrt(64) * log2(e) so attention inner loop is exp2 only.
#define QSCALE 0.18033688f

static __device__ __forceinline__ unsigned short f2bf(float f) {
  __hip_bfloat16 h = __float2bfloat16(f);
  union { __hip_bfloat16 h; unsigned short u; } cv;
  cv.h = h;
  return cv.u;
}

typedef const __attribute__((address_space(1))) unsigned int* gp_t;
typedef __attribute__((address_space(3))) unsigned int* lp_t;
static __device__ __forceinline__ void gload_lds16(const void* g, void* l) {
  __builtin_amdgcn_global_load_lds((gp_t)g, (lp_t)l, 16, 0, 0);
}

// ---------------------------------------------------------------------------
// Weight transpose: W [K][N] fp32 -> WT [N][K] bf16. 64x64 tiles, 256 thr.
// ---------------------------------------------------------------------------
__global__ __launch_bounds__(256) void transpose_w(
    const float* __restrict__ W, unsigned short* __restrict__ WT, int K, int N) {
  __shared__ float T[64][65];
  const int tid = threadIdx.x;
  const int n0 = blockIdx.x * 64;
  const int k0 = blockIdx.y * 64;
#pragma unroll
  for (int it = 0; it < 4; it++) {
    int row = it * 16 + (tid >> 4);     // k within tile
    int c4 = (tid & 15) * 4;            // n within tile
    f32x4 v = *(const f32x4*)&W[(size_t)(k0 + row) * N + n0 + c4];
#pragma unroll
    for (int j = 0; j < 4; j++) T[row][c4 + j] = v[j];
  }
  __syncthreads();
#pragma unroll
  for (int it = 0; it < 2; it++) {
    int chunk = tid + it * 256;         // 512 chunks of short8
    int n = chunk >> 3;
    int c8 = (chunk & 7) * 8;           // k within tile
    short8 s;
#pragma unroll
    for (int j = 0; j < 8; j++) s[j] = (short)f2bf(T[c8 + j][n]);
    *(short8*)&WT[(size_t)(n0 + n) * K + k0 + c8] = s;
  }
}

// ---------------------------------------------------------------------------
// GEMM: C[M,N] = A[M,K] @ BT[N,K]^T, fp32 accum.  128x128 tile, BK=32,
// 256 threads (4 waves 2x2).  BT is bf16 [N][K] (k-contig) -> global_load_lds.
// MODE 0: A fp32 (x); scatter epilogue into Q/K/V bf16 (Q scaled by QSCALE).
// MODE 1: A bf16 (ctx), staged via global_load_lds; fp32 row-major output.
// ---------------------------------------------------------------------------
template <int MODE>
__global__ __launch_bounds__(256) void gemm_kernel(
    const void* __restrict__ Av, const unsigned short* __restrict__ BT,
    unsigned short* __restrict__ out0, unsigned short* __restrict__ out1,
    unsigned short* __restrict__ out2, float* __restrict__ outf,
    int M, int N, int K) {
  __shared__ unsigned short As[128][32];  // As[m][k] (bf16)  -- no padding!
  __shared__ unsigned short Bs[128][32];  // Bs[n][k] (bf16)

  const int tid = threadIdx.x;
  const int wave = tid >> 6;
  const int lane = tid & 63;
  const int quad = lane >> 4;
  const int lc = lane & 15;
  const int wr = wave >> 1;
  const int wc = wave & 1;
  const int m0 = blockIdx.y * 128;
  const int n0 = blockIdx.x * 128;

  f32x4 acc[4][4];
#pragma unroll
  for (int i = 0; i < 4; i++)
#pragma unroll
    for (int j = 0; j < 4; j++) acc[i][j] = (f32x4){0.f, 0.f, 0.f, 0.f};

  for (int k0 = 0; k0 < K; k0 += 32) {
    // ---- Stage A tile (128 x 32) ----
    if (MODE == 0) {
      const float* A = (const float*)Av;
#pragma unroll
      for (int i = 0; i < 4; i++) {
        int chunk = tid + i * 256;
        int r = chunk >> 3;
        int c4 = (chunk & 7) * 4;
        f32x4 v = *(const f32x4*)&A[(size_t)(m0 + r) * K + k0 + c4];
        short4v s;
#pragma unroll
        for (int j = 0; j < 4; j++) s[j] = (short)f2bf(v[j]);
        *(short4v*)&As[r][c4] = s;
      }
    } else {
      const unsigned short* A = (const unsigned short*)Av;
#pragma unroll
      for (int it = 0; it < 2; it++) {
        int rbase = wave * 32 + it * 16;  // 16 rows = 1 KB per instruction
        gload_lds16(&A[(size_t)(m0 + rbase + (lane >> 2)) * K + k0 + (lane & 3) * 8],
                    &As[rbase][0]);
      }
    }
    // ---- Stage B tile (128 n-rows x 32 k) via async direct-to-LDS ----
#pragma unroll
    for (int it = 0; it < 2; it++) {
      int rbase = wave * 32 + it * 16;
      gload_lds16(&BT[(size_t)(n0 + rbase + (lane >> 2)) * K + k0 + (lane & 3) * 8],
                  &Bs[rbase][0]);
    }
    __syncthreads();

    short8 aA[4], bB[4];
#pragma unroll
    for (int mt = 0; mt < 4; mt++)
      aA[mt] = *(const short8*)&As[wr * 64 + mt * 16 + lc][quad * 8];
#pragma unroll
    for (int nt = 0; nt < 4; nt++)
      bB[nt] = *(const short8*)&Bs[wc * 64 + nt * 16 + lc][quad * 8];
#pragma unroll
    for (int mt = 0; mt < 4; mt++)
#pragma unroll
      for (int nt = 0; nt < 4; nt++)
        acc[mt][nt] = __builtin_amdgcn_mfma_f32_16x16x32_bf16(
            aA[mt], bB[nt], acc[mt][nt], 0, 0, 0);
    __syncthreads();
  }

  // Epilogue: C/D layout col=lane&15, row=quad*4+reg.
#pragma unroll
  for (int mt = 0; mt < 4; mt++)
#pragma unroll
    for (int nt = 0; nt < 4; nt++)
#pragma unroll
      for (int r = 0; r < 4; r++) {
        int row = m0 + wr * 64 + mt * 16 + quad * 4 + r;
        int col = n0 + wc * 64 + nt * 16 + lc;
        float v = acc[mt][nt][r];
        if (MODE == 0) {
          int c = col >> 10;       // 0=Q 1=K 2=V
          int rem = col & 1023;
          int h = rem >> 6;
          int dd = rem & 63;
          int b = row >> 11;
          int tt = row & 2047;
          if (c == 0) v *= QSCALE;
          unsigned short* dst = (c == 0) ? out0 : ((c == 1) ? out1 : out2);
          dst[(((size_t)(b * NH + h) * SEQ + tt) << 6) + dd] = f2bf(v);
        } else {
          outf[(size_t)row * N + col] = v;
        }
      }
}

// ---------------------------------------------------------------------------
// Flash attention, head-major Q/K/V [BH=64][T=2048][64] bf16. Q pre-scaled.
// 256 threads = 4 waves; wave owns 16 q-rows. 64-key tiles; max-free
// deferred softmax (p = exp2(s), l summed per-lane, reduced once at end).
// Vst stored with XOR-swizzled key blocks for conflict-free transpose.
// ---------------------------------------------------------------------------
__global__ __launch_bounds__(256) void attn_kernel(
    const unsigned short* __restrict__ Q, const unsigned short* __restrict__ K,
    const unsigned short* __restrict__ V, unsigned short* __restrict__ ctx) {
  __shared__ unsigned short Ks[64][72];     // Ks[key][d], padded
  __shared__ unsigned short Vst[64][72];    // Vst[d][key^swz], padded
  __shared__ unsigned short Ps[4][16][72];  // per-wave P[qrow][key], padded

  const int tid = threadIdx.x;
  const int wave = tid >> 6;
  const int lane = tid & 63;
  const int quad = lane >> 4;
  const int lc = lane & 15;
  const int bh = blockIdx.y;
  const int q0 = blockIdx.x * 64 + wave * 16;
  const size_t base = (size_t)bh * SEQ * DH;

  const short8 aQ0 = *(const short8*)&Q[base + (size_t)(q0 + lc) * DH + quad * 8];
  const short8 aQ1 =
      *(const short8*)&Q[base + (size_t)(q0 + lc) * DH + 32 + quad * 8];

  float l_part[4] = {0.f, 0.f, 0.f, 0.f};
  f32x4 o[4];
#pragma unroll
  for (int nt = 0; nt < 4; nt++) o[nt] = (f32x4){0.f, 0.f, 0.f, 0.f};

  for (int kt = 0; kt < SEQ / 64; kt++) {
    const size_t kbase = base + (size_t)kt * 64 * DH;
    // Stage K (direct) and V (transposed, swizzled): 64 rows x 64 d.
#pragma unroll
    for (int it = 0; it < 2; it++) {
      int chunk = tid + it * 256;
      int row = chunk >> 3;          // key
      int l3 = chunk & 7;            // d-block
      int c8 = l3 * 8;               // d base
      *(short8*)&Ks[row][c8] = *(const short8*)&K[kbase + (size_t)row * DH + c8];
      short8 v = *(const short8*)&V[kbase + (size_t)row * DH + c8];
      int krow = row ^ (l3 << 3);    // swizzled key column
#pragma unroll
      for (int j = 0; j < 8; j++) Vst[c8 + j][krow] = (unsigned short)v[j];
    }
    __syncthreads();

    // S = Q K^T : 4 column tiles of 16 keys, contraction d=64 (2 MFMA each).
    f32x4 s[4];
#pragma unroll
    for (int c = 0; c < 4; c++) {
      const short8 bK0 = *(const short8*)&Ks[c * 16 + lc][quad * 8];
      const short8 bK1 = *(const short8*)&Ks[c * 16 + lc][32 + quad * 8];
      s[c] = __builtin_amdgcn_mfma_f32_16x16x32_bf16(
          aQ0, bK0, (f32x4){0.f, 0.f, 0.f, 0.f}, 0, 0, 0);
      s[c] = __builtin_amdgcn_mfma_f32_16x16x32_bf16(aQ1, bK1, s[c], 0, 0, 0);
    }
    // Max-free softmax: p = exp2(s) (Q pre-scaled); defer l reduction.
#pragma unroll
    for (int c = 0; c < 4; c++)
#pragma unroll
      for (int r = 0; r < 4; r++) {
        float p = exp2f(s[c][r]);
        l_part[r] += p;
        Ps[wave][quad * 4 + r][c * 16 + lc] = f2bf(p);
      }
    // PV: contraction over 64 keys (2 halves of 32).
#pragma unroll
    for (int half = 0; half < 2; half++) {
      const short8 pA =
          *(const short8*)&Ps[wave][lc][half * 32 + quad * 8];
#pragma unroll
      for (int nt = 0; nt < 4; nt++) {
        int d = nt * 16 + lc;
        int blk = (half * 4 + quad) ^ ((d >> 3) & 7);
        const short8 bV = *(const short8*)&Vst[d][blk * 8];
        o[nt] = __builtin_amdgcn_mfma_f32_16x16x32_bf16(pA, bV, o[nt], 0, 0, 0);
      }
    }
    __syncthreads();
  }

  // Final l reduction over the 16-lane row group (once per block).
  float inv[4];
#pragma unroll
  for (int r = 0; r < 4; r++) {
    float l = l_part[r];
#pragma unroll
    for (int off = 1; off < 16; off <<= 1) l += __shfl_xor(l, off);
    inv[r] = 1.0f / l;
  }

  const int b = bh >> 4;
  const int h = bh & 15;
#pragma unroll
  for (int nt = 0; nt < 4; nt++)
#pragma unroll
    for (int r = 0; r < 4; r++) {
      int trow = q0 + quad * 4 + r;
      int d = nt * 16 + lc;
      ctx[(size_t)(b * SEQ + trow) * DM + h * DH + d] = f2bf(o[nt][r] * inv[r]);
    }
}

extern "C" void kernel_launch(void* const* d_in, const int* in_sizes, int n_in,
                              void* d_out, int out_size, void* d_ws,
                              size_t ws_size, hipStream_t stream) {
  const float* x = (const float*)d_in[0];     // [8192,1024] fp32
  const float* Wqkv = (const float*)d_in[1];  // [1024,3072] fp32
  const float* Wo = (const float*)d_in[2];    // [1024,1024] fp32
  float* out = (float*)d_out;                 // [8192,1024] fp32
  unsigned short* ws = (unsigned short*)d_ws;

  unsigned short* Qb = ws;             // bf16, Q pre-scaled
  unsigned short* Kb = ws + SEG;
  unsigned short* Vb = ws + 2 * SEG;
  unsigned short* Ctx = ws + 3 * SEG;  // [8192,1024] bf16
  unsigned short* WqT = ws + 4 * SEG;  // [3072,1024] bf16
  unsigned short* WoT = WqT + (size_t)3 * DM * DM;  // [1024,1024] bf16

  // 0) transpose weights to bf16 [N][K]
  transpose_w<<<dim3(3 * DM / 64, DM / 64), 256, 0, stream>>>(Wqkv, WqT, DM, 3 * DM);
  transpose_w<<<dim3(DM / 64, DM / 64), 256, 0, stream>>>(Wo, WoT, DM, DM);
  // 1) qkv = x @ W_qkv -> head-major Q/K/V (Q scaled)
  gemm_kernel<0><<<dim3(3 * DM / 128, MTOK / 128), 256, 0, stream>>>(
      (const void*)x, WqT, Qb, Kb, Vb, nullptr, MTOK, 3 * DM, DM);
  // 2) attention
  attn_kernel<<<dim3(SEQ / 64, NBATCH * NH), 256, 0, stream>>>(Qb, Kb, Vb, Ctx);
  // 3) out = ctx @ W_o (fp32 out)
  gemm_kernel<1><<<dim3(DM / 128, MTOK / 128), 256, 0, stream>>>(
      (const void*)Ctx, WoT, nullptr, nullptr, nullptr, out, MTOK, DM, DM);
}

// Round 5
// 309.452 us; speedup vs baseline: 3.3660x; 1.1804x over previous
//
#include <hip/hip_runtime.h>
#include <hip/hip_bf16.h>

typedef __attribute__((ext_vector_type(8))) short short8;
typedef __attribute__((ext_vector_type(4))) short short4v;
typedef __attribute__((ext_vector_type(4))) float f32x4;
typedef __attribute__((ext_vector_type(16))) float f32x16;

#define SEQ    2048
#define DM     1024
#define NH     16
#define DH     64
#define NBATCH 4
#define MTOK   (NBATCH * SEQ)                       // 8192 tokens
#define SEG    ((size_t)NBATCH * NH * SEQ * DH)     // 8388608 elems per Q/K/V buffer
// Q pre-scaled by 1/sqrt(64) * log2(e) so attention inner loop is exp2 only.
#define QSCALE 0.18033688f

static __device__ __forceinline__ unsigned short f2bf(float f) {
  __hip_bfloat16 h = __float2bfloat16(f);
  union { __hip_bfloat16 h; unsigned short u; } cv;
  cv.h = h;
  return cv.u;
}

typedef const __attribute__((address_space(1))) unsigned int* gp_t;
typedef __attribute__((address_space(3))) unsigned int* lp_t;
static __device__ __forceinline__ void gload_lds16(const void* g, void* l) {
  __builtin_amdgcn_global_load_lds((gp_t)g, (lp_t)l, 16, 0, 0);
}

// ---------------------------------------------------------------------------
// x fp32 -> bf16 cast (8 elems/thread).
// ---------------------------------------------------------------------------
__global__ __launch_bounds__(256) void xcast(const float* __restrict__ x,
                                             unsigned short* __restrict__ xb) {
  size_t i = ((size_t)blockIdx.x * 256 + threadIdx.x) * 8;
  f32x4 a = *(const f32x4*)&x[i];
  f32x4 b = *(const f32x4*)&x[i + 4];
  short8 s;
#pragma unroll
  for (int j = 0; j < 4; j++) {
    s[j] = (short)f2bf(a[j]);
    s[4 + j] = (short)f2bf(b[j]);
  }
  *(short8*)&xb[i] = s;
}

// ---------------------------------------------------------------------------
// Weight transpose: W [K][N] fp32 -> WT [N][K] bf16. 64x64 tiles, 256 thr.
// ---------------------------------------------------------------------------
__global__ __launch_bounds__(256) void transpose_w(
    const float* __restrict__ W, unsigned short* __restrict__ WT, int K, int N) {
  __shared__ float T[64][65];
  const int tid = threadIdx.x;
  const int n0 = blockIdx.x * 64;
  const int k0 = blockIdx.y * 64;
#pragma unroll
  for (int it = 0; it < 4; it++) {
    int row = it * 16 + (tid >> 4);
    int c4 = (tid & 15) * 4;
    f32x4 v = *(const f32x4*)&W[(size_t)(k0 + row) * N + n0 + c4];
#pragma unroll
    for (int j = 0; j < 4; j++) T[row][c4 + j] = v[j];
  }
  __syncthreads();
#pragma unroll
  for (int it = 0; it < 2; it++) {
    int chunk = tid + it * 256;
    int n = chunk >> 3;
    int c8 = (chunk & 7) * 8;
    short8 s;
#pragma unroll
    for (int j = 0; j < 8; j++) s[j] = (short)f2bf(T[c8 + j][n]);
    *(short8*)&WT[(size_t)(n0 + n) * K + k0 + c8] = s;
  }
}

// ---------------------------------------------------------------------------
// GEMM: C[M,N] = A[M,K] @ BT[N,K]^T, fp32 accum. 128x128 tile, BK=32,
// 256 threads (4 waves 2x2). BT bf16 [N][K] staged via global_load_lds.
// MODE 0: A fp32 (VALU cvt staging); QKV scatter epilogue (V transposed).
// MODE 2: A bf16 (DMA staging);      QKV scatter epilogue (V transposed).
// MODE 1: A bf16 (DMA staging);      fp32 row-major output.
// QKV epilogue: Q -> out0 [bh][T][64] (scaled), K -> out1 [bh][T][64],
//               V -> out2 [bh][64][T] (transposed, packed 4-token stores).
// ---------------------------------------------------------------------------
template <int MODE>
__global__ __launch_bounds__(256) void gemm_kernel(
    const void* __restrict__ Av, const unsigned short* __restrict__ BT,
    unsigned short* __restrict__ out0, unsigned short* __restrict__ out1,
    unsigned short* __restrict__ out2, float* __restrict__ outf,
    int M, int N, int K) {
  __shared__ unsigned short As[128][32];
  __shared__ unsigned short Bs[128][32];

  const int tid = threadIdx.x;
  const int wave = tid >> 6;
  const int lane = tid & 63;
  const int quad = lane >> 4;
  const int lc = lane & 15;
  const int wr = wave >> 1;
  const int wc = wave & 1;
  const int m0 = blockIdx.y * 128;
  const int n0 = blockIdx.x * 128;

  f32x4 acc[4][4];
#pragma unroll
  for (int i = 0; i < 4; i++)
#pragma unroll
    for (int j = 0; j < 4; j++) acc[i][j] = (f32x4){0.f, 0.f, 0.f, 0.f};

  for (int k0 = 0; k0 < K; k0 += 32) {
    if (MODE == 0) {
      const float* A = (const float*)Av;
#pragma unroll
      for (int i = 0; i < 4; i++) {
        int chunk = tid + i * 256;
        int r = chunk >> 3;
        int c4 = (chunk & 7) * 4;
        f32x4 v = *(const f32x4*)&A[(size_t)(m0 + r) * K + k0 + c4];
        short4v s;
#pragma unroll
        for (int j = 0; j < 4; j++) s[j] = (short)f2bf(v[j]);
        *(short4v*)&As[r][c4] = s;
      }
    } else {
      const unsigned short* A = (const unsigned short*)Av;
#pragma unroll
      for (int it = 0; it < 2; it++) {
        int rbase = wave * 32 + it * 16;
        gload_lds16(&A[(size_t)(m0 + rbase + (lane >> 2)) * K + k0 + (lane & 3) * 8],
                    &As[rbase][0]);
      }
    }
#pragma unroll
    for (int it = 0; it < 2; it++) {
      int rbase = wave * 32 + it * 16;
      gload_lds16(&BT[(size_t)(n0 + rbase + (lane >> 2)) * K + k0 + (lane & 3) * 8],
                  &Bs[rbase][0]);
    }
    __syncthreads();

    short8 aA[4], bB[4];
#pragma unroll
    for (int mt = 0; mt < 4; mt++)
      aA[mt] = *(const short8*)&As[wr * 64 + mt * 16 + lc][quad * 8];
#pragma unroll
    for (int nt = 0; nt < 4; nt++)
      bB[nt] = *(const short8*)&Bs[wc * 64 + nt * 16 + lc][quad * 8];
#pragma unroll
    for (int mt = 0; mt < 4; mt++)
#pragma unroll
      for (int nt = 0; nt < 4; nt++)
        acc[mt][nt] = __builtin_amdgcn_mfma_f32_16x16x32_bf16(
            aA[mt], bB[nt], acc[mt][nt], 0, 0, 0);
    __syncthreads();
  }

  // Epilogue: C/D layout col=lane&15, row=quad*4+reg.
  const int c = n0 >> 10;  // QKV segment (block-uniform): 0=Q 1=K 2=V
#pragma unroll
  for (int mt = 0; mt < 4; mt++)
#pragma unroll
    for (int nt = 0; nt < 4; nt++) {
      int rb = m0 + wr * 64 + mt * 16 + quad * 4;  // 4 consecutive tokens
      int col = n0 + wc * 64 + nt * 16 + lc;
      if (MODE == 1) {
#pragma unroll
        for (int r = 0; r < 4; r++)
          outf[(size_t)(rb + r) * N + col] = acc[mt][nt][r];
      } else {
        int rem = col & 1023;
        int h = rem >> 6;
        int dd = rem & 63;
        int b = rb >> 11;
        int tt = rb & 2047;
        if (c == 2) {
          short4v pk;
#pragma unroll
          for (int r = 0; r < 4; r++) pk[r] = (short)f2bf(acc[mt][nt][r]);
          *(short4v*)&out2[(((size_t)(b * NH + h)) * DH + dd) * SEQ + tt] = pk;
        } else {
          unsigned short* dst = (c == 0) ? out0 : out1;
          float sc = (c == 0) ? QSCALE : 1.0f;
#pragma unroll
          for (int r = 0; r < 4; r++)
            dst[(((size_t)(b * NH + h) * SEQ + tt + r) << 6) + dd] =
                f2bf(acc[mt][nt][r] * sc);
        }
      }
    }
}

// ---------------------------------------------------------------------------
// Flash attention. Q,K: [bh][T][64] bf16 (Q pre-scaled); Vt: [bh][64][T] bf16.
// Block = 256 thr = 4 waves; wave owns 32 q-rows (block 128); 64-key tiles.
// S^T = K·Q^T via 32x32x16 MFMA (A=K, B=Q) -> C layout col=qrow gives 4
// consecutive keys per lane -> packed b64 P spills. Max-free deferred softmax.
// K/Vt staged by global_load_lds with granule-XOR swizzle (no VALU, low bank
// conflict). PV: O = P·V via A=P(from LDS), B=Vt rows.
// ---------------------------------------------------------------------------
__global__ __launch_bounds__(256) void attn_kernel(
    const unsigned short* __restrict__ Q, const unsigned short* __restrict__ K,
    const unsigned short* __restrict__ Vt, unsigned short* __restrict__ ctx) {
  __shared__ unsigned short KsL[64 * 64];   // granule-swizzled [key][d]
  __shared__ unsigned short VtL[64 * 64];   // granule-swizzled [d][key]
  __shared__ unsigned short Ps[4][32][72];  // per-wave P[qrow][key]
  __shared__ float lbuf[4][32];

  const int tid = threadIdx.x;
  const int wave = tid >> 6;
  const int lane = tid & 63;
  const int half = lane >> 5;
  const int l31 = lane & 31;
  const int bh = blockIdx.y;
  const int q0 = blockIdx.x * 128 + wave * 32;
  const size_t kqbase = (size_t)bh * SEQ * DH;
  const size_t vbase = (size_t)bh * DH * SEQ;

  // Q B-fragments (n=qrow=l31, k=d): 4 d-chunks of 16.
  short8 bQ[4];
#pragma unroll
  for (int dc = 0; dc < 4; dc++)
    bQ[dc] = *(const short8*)&Q[kqbase + (size_t)(q0 + l31) * DH + dc * 16 + half * 8];

  f32x16 o[2];
#pragma unroll
  for (int nb = 0; nb < 2; nb++)
#pragma unroll
    for (int j = 0; j < 16; j++) o[nb][j] = 0.f;
  float l_part = 0.f;

  const int xsw = l31 & 7;  // bank-swizzle key for this lane's fragment rows

  for (int kt = 0; kt < SEQ / 64; kt++) {
    const size_t kg = kqbase + (size_t)kt * 64 * DH;
    const size_t vg = vbase + (size_t)kt * 64;
    // Stage K (64key x 64d) and Vt (64d x 64key): 16B granules, XOR-swizzled.
#pragma unroll
    for (int it = 0; it < 2; it++) {
      int g = wave * 128 + it * 64 + lane;  // granule id 0..511
      int row = g >> 3;                     // key (K) / d (Vt)
      int goff = ((g & 7) ^ (row & 7)) * 8; // swizzled source offset
      gload_lds16(&K[kg + (size_t)row * DH + goff],
                  &KsL[(size_t)(wave * 128 + it * 64) * 8]);
      gload_lds16(&Vt[vg + (size_t)row * SEQ + goff],
                  &VtL[(size_t)(wave * 128 + it * 64) * 8]);
    }
    __syncthreads();

    // S^T = K·Q^T : two 32-key blocks, contraction d=64 (4 chained MFMA).
#pragma unroll
    for (int kb = 0; kb < 2; kb++) {
      f32x16 s;
#pragma unroll
      for (int j = 0; j < 16; j++) s[j] = 0.f;
#pragma unroll
      for (int dc = 0; dc < 4; dc++) {
        const short8 aK = *(const short8*)&KsL[(size_t)(kb * 32 + l31) * 64 +
                                               ((dc * 2 + half) ^ xsw) * 8];
        s = __builtin_amdgcn_mfma_f32_32x32x16_bf16(aK, bQ[dc], s, 0, 0, 0);
      }
      // p = exp2(s); pack 4 consecutive keys per b64 write.
#pragma unroll
      for (int gq = 0; gq < 4; gq++) {
        short4v pk;
#pragma unroll
        for (int j = 0; j < 4; j++) {
          float p = exp2f(s[gq * 4 + j]);
          l_part += p;
          pk[j] = (short)f2bf(p);
        }
        *(short4v*)&Ps[wave][l31][kb * 32 + gq * 8 + half * 4] = pk;
      }
    }

    // O += P·V : contraction key=64 (4 chunks of 16), 2 d-blocks of 32.
#pragma unroll
    for (int kc = 0; kc < 4; kc++) {
      const short8 pA = *(const short8*)&Ps[wave][l31][kc * 16 + half * 8];
#pragma unroll
      for (int nb = 0; nb < 2; nb++) {
        const short8 bV = *(const short8*)&VtL[(size_t)(nb * 32 + l31) * 64 +
                                               ((kc * 2 + half) ^ xsw) * 8];
        o[nb] = __builtin_amdgcn_mfma_f32_32x32x16_bf16(pA, bV, o[nb], 0, 0, 0);
      }
    }
    __syncthreads();
  }

  // l: both halves hold partial sums for qrow=l31 -> combine, share via LDS.
  l_part += __shfl_xor(l_part, 32);
  lbuf[wave][l31] = l_part;
  __syncthreads();

  const int b = bh >> 4;
  const int h = bh & 15;
#pragma unroll
  for (int gq = 0; gq < 4; gq++)
#pragma unroll
    for (int j = 0; j < 4; j++) {
      int ql = j + gq * 8 + half * 4;  // q within wave (C-layout row)
      float inv = 1.0f / lbuf[wave][ql];
      int token = blockIdx.x * 128 + wave * 32 + ql;
#pragma unroll
      for (int nb = 0; nb < 2; nb++)
        ctx[((size_t)b * SEQ + token) * DM + h * DH + nb * 32 + l31] =
            f2bf(o[nb][gq * 4 + j] * inv);
    }
}

extern "C" void kernel_launch(void* const* d_in, const int* in_sizes, int n_in,
                              void* d_out, int out_size, void* d_ws,
                              size_t ws_size, hipStream_t stream) {
  const float* x = (const float*)d_in[0];     // [8192,1024] fp32
  const float* Wqkv = (const float*)d_in[1];  // [1024,3072] fp32
  const float* Wo = (const float*)d_in[2];    // [1024,1024] fp32
  float* out = (float*)d_out;                 // [8192,1024] fp32
  unsigned short* ws = (unsigned short*)d_ws;

  unsigned short* Qb = ws;                          // [bh][T][64], pre-scaled
  unsigned short* Kb = ws + SEG;                    // [bh][T][64]
  unsigned short* Vt = ws + 2 * SEG;                // [bh][64][T]
  unsigned short* Ctx = ws + 3 * SEG;               // [8192][1024]
  unsigned short* WqT = Ctx + (size_t)MTOK * DM;    // [3072][1024]
  unsigned short* WoT = WqT + (size_t)3 * DM * DM;  // [1024][1024]
  unsigned short* Xb = WoT + (size_t)DM * DM;       // [8192][1024]
  const size_t need =
      ((size_t)(Xb - ws) + (size_t)MTOK * DM) * sizeof(unsigned short);

  transpose_w<<<dim3(3 * DM / 64, DM / 64), 256, 0, stream>>>(Wqkv, WqT, DM, 3 * DM);
  transpose_w<<<dim3(DM / 64, DM / 64), 256, 0, stream>>>(Wo, WoT, DM, DM);

  if (ws_size >= need) {
    xcast<<<(MTOK * DM) / (256 * 8), 256, 0, stream>>>(x, Xb);
    gemm_kernel<2><<<dim3(3 * DM / 128, MTOK / 128), 256, 0, stream>>>(
        (const void*)Xb, WqT, Qb, Kb, Vt, nullptr, MTOK, 3 * DM, DM);
  } else {
    gemm_kernel<0><<<dim3(3 * DM / 128, MTOK / 128), 256, 0, stream>>>(
        (const void*)x, WqT, Qb, Kb, Vt, nullptr, MTOK, 3 * DM, DM);
  }
  attn_kernel<<<dim3(SEQ / 128, NBATCH * NH), 256, 0, stream>>>(Qb, Kb, Vt, Ctx);
  gemm_kernel<1><<<dim3(DM / 128, MTOK / 128), 256, 0, stream>>>(
      (const void*)Ctx, WoT, nullptr, nullptr, nullptr, out, MTOK, DM, DM);
}

// Round 6
// 297.841 us; speedup vs baseline: 3.4972x; 1.0390x over previous
//
#include <hip/hip_runtime.h>
#include <hip/hip_bf16.h>

typedef __attribute__((ext_vector_type(8))) short short8;
typedef __attribute__((ext_vector_type(4))) short short4v;
typedef __attribute__((ext_vector_type(4))) float f32x4;
typedef __attribute__((ext_vector_type(16))) float f32x16;
typedef __attribute__((ext_vector_type(2))) unsigned int uint2v;
typedef __attribute__((ext_vector_type(4))) unsigned int uint4v;

#define SEQ    2048
#define DM     1024
#define NH     16
#define DH     64
#define NBATCH 4
#define MTOK   (NBATCH * SEQ)                       // 8192 tokens
#define SEG    ((size_t)NBATCH * NH * SEQ * DH)     // 8388608 elems per Q/K/V buffer
// Q pre-scaled by 1/sqrt(64) * log2(e) so attention inner loop is exp2 only.
#define QSCALE 0.18033688f

// Fast RNE float->bf16 for FINITE values: bf16 bits land in the high 16.
static __device__ __forceinline__ unsigned bfbits(float f) {
  unsigned u = __float_as_uint(f);
  return u + 0x7fffu + ((u >> 16) & 1u);
}
static __device__ __forceinline__ unsigned short f2bf(float f) {
  return (unsigned short)(bfbits(f) >> 16);
}
// Pack bf16(lo) into low half, bf16(hi) into high half with one v_perm.
static __device__ __forceinline__ unsigned pack2bf(float lo, float hi) {
  return __builtin_amdgcn_perm(bfbits(hi), bfbits(lo), 0x07060302u);
}

typedef const __attribute__((address_space(1))) unsigned int* gp_t;
typedef __attribute__((address_space(3))) unsigned int* lp_t;
static __device__ __forceinline__ void gload_lds16(const void* g, void* l) {
  __builtin_amdgcn_global_load_lds((gp_t)g, (lp_t)l, 16, 0, 0);
}

// ---------------------------------------------------------------------------
// x fp32 -> bf16 cast (8 elems/thread).
// ---------------------------------------------------------------------------
__global__ __launch_bounds__(256) void xcast(const float* __restrict__ x,
                                             unsigned short* __restrict__ xb) {
  size_t i = ((size_t)blockIdx.x * 256 + threadIdx.x) * 8;
  f32x4 a = *(const f32x4*)&x[i];
  f32x4 b = *(const f32x4*)&x[i + 4];
  uint4v s;
  s[0] = pack2bf(a[0], a[1]);
  s[1] = pack2bf(a[2], a[3]);
  s[2] = pack2bf(b[0], b[1]);
  s[3] = pack2bf(b[2], b[3]);
  *(uint4v*)&xb[i] = s;
}

// ---------------------------------------------------------------------------
// Weight transpose: W [K][N] fp32 -> WT [N][K] bf16. 64x64 tiles, 256 thr.
// ---------------------------------------------------------------------------
__global__ __launch_bounds__(256) void transpose_w(
    const float* __restrict__ W, unsigned short* __restrict__ WT, int K, int N) {
  __shared__ float T[64][65];
  const int tid = threadIdx.x;
  const int n0 = blockIdx.x * 64;
  const int k0 = blockIdx.y * 64;
#pragma unroll
  for (int it = 0; it < 4; it++) {
    int row = it * 16 + (tid >> 4);
    int c4 = (tid & 15) * 4;
    f32x4 v = *(const f32x4*)&W[(size_t)(k0 + row) * N + n0 + c4];
#pragma unroll
    for (int j = 0; j < 4; j++) T[row][c4 + j] = v[j];
  }
  __syncthreads();
#pragma unroll
  for (int it = 0; it < 2; it++) {
    int chunk = tid + it * 256;
    int n = chunk >> 3;
    int c8 = (chunk & 7) * 8;
    uint4v s;
#pragma unroll
    for (int j = 0; j < 4; j++)
      s[j] = pack2bf(T[c8 + 2 * j][n], T[c8 + 2 * j + 1][n]);
    *(uint4v*)&WT[(size_t)(n0 + n) * K + k0 + c8] = s;
  }
}

// ---------------------------------------------------------------------------
// GEMM: C[M,N] = A[M,K] @ BT[N,K]^T, fp32 accum. 128x128 tile, BK=32,
// 256 threads (4 waves 2x2). BT bf16 [N][K] staged via global_load_lds.
// MODE 0: A fp32 (VALU cvt staging); QKV scatter epilogue (V transposed).
// MODE 2: A bf16 (DMA staging);      QKV scatter epilogue (V transposed).
// MODE 1: A bf16 (DMA staging);      fp32 row-major output.
// QKV epilogue: Q -> out0 [bh][T][64] (scaled), K -> out1 [bh][T][64],
//               V -> out2 [bh][64][T] (transposed, packed 4-token stores).
// ---------------------------------------------------------------------------
template <int MODE>
__global__ __launch_bounds__(256) void gemm_kernel(
    const void* __restrict__ Av, const unsigned short* __restrict__ BT,
    unsigned short* __restrict__ out0, unsigned short* __restrict__ out1,
    unsigned short* __restrict__ out2, float* __restrict__ outf,
    int M, int N, int K) {
  __shared__ unsigned short As[128][32];
  __shared__ unsigned short Bs[128][32];

  const int tid = threadIdx.x;
  const int wave = tid >> 6;
  const int lane = tid & 63;
  const int quad = lane >> 4;
  const int lc = lane & 15;
  const int wr = wave >> 1;
  const int wc = wave & 1;
  const int m0 = blockIdx.y * 128;
  const int n0 = blockIdx.x * 128;

  f32x4 acc[4][4];
#pragma unroll
  for (int i = 0; i < 4; i++)
#pragma unroll
    for (int j = 0; j < 4; j++) acc[i][j] = (f32x4){0.f, 0.f, 0.f, 0.f};

  for (int k0 = 0; k0 < K; k0 += 32) {
    if (MODE == 0) {
      const float* A = (const float*)Av;
#pragma unroll
      for (int i = 0; i < 4; i++) {
        int chunk = tid + i * 256;
        int r = chunk >> 3;
        int c4 = (chunk & 7) * 4;
        f32x4 v = *(const f32x4*)&A[(size_t)(m0 + r) * K + k0 + c4];
        uint2v s;
        s[0] = pack2bf(v[0], v[1]);
        s[1] = pack2bf(v[2], v[3]);
        *(uint2v*)&As[r][c4] = s;
      }
    } else {
      const unsigned short* A = (const unsigned short*)Av;
#pragma unroll
      for (int it = 0; it < 2; it++) {
        int rbase = wave * 32 + it * 16;
        gload_lds16(&A[(size_t)(m0 + rbase + (lane >> 2)) * K + k0 + (lane & 3) * 8],
                    &As[rbase][0]);
      }
    }
#pragma unroll
    for (int it = 0; it < 2; it++) {
      int rbase = wave * 32 + it * 16;
      gload_lds16(&BT[(size_t)(n0 + rbase + (lane >> 2)) * K + k0 + (lane & 3) * 8],
                  &Bs[rbase][0]);
    }
    __syncthreads();

    short8 aA[4], bB[4];
#pragma unroll
    for (int mt = 0; mt < 4; mt++)
      aA[mt] = *(const short8*)&As[wr * 64 + mt * 16 + lc][quad * 8];
#pragma unroll
    for (int nt = 0; nt < 4; nt++)
      bB[nt] = *(const short8*)&Bs[wc * 64 + nt * 16 + lc][quad * 8];
#pragma unroll
    for (int mt = 0; mt < 4; mt++)
#pragma unroll
      for (int nt = 0; nt < 4; nt++)
        acc[mt][nt] = __builtin_amdgcn_mfma_f32_16x16x32_bf16(
            aA[mt], bB[nt], acc[mt][nt], 0, 0, 0);
    __syncthreads();
  }

  // Epilogue: C/D layout col=lane&15, row=quad*4+reg.
  const int c = n0 >> 10;  // QKV segment (block-uniform): 0=Q 1=K 2=V
#pragma unroll
  for (int mt = 0; mt < 4; mt++)
#pragma unroll
    for (int nt = 0; nt < 4; nt++) {
      int rb = m0 + wr * 64 + mt * 16 + quad * 4;  // 4 consecutive tokens
      int col = n0 + wc * 64 + nt * 16 + lc;
      if (MODE == 1) {
#pragma unroll
        for (int r = 0; r < 4; r++)
          outf[(size_t)(rb + r) * N + col] = acc[mt][nt][r];
      } else {
        int rem = col & 1023;
        int h = rem >> 6;
        int dd = rem & 63;
        int b = rb >> 11;
        int tt = rb & 2047;
        if (c == 2) {
          uint2v pk;
          pk[0] = pack2bf(acc[mt][nt][0], acc[mt][nt][1]);
          pk[1] = pack2bf(acc[mt][nt][2], acc[mt][nt][3]);
          *(uint2v*)&out2[(((size_t)(b * NH + h)) * DH + dd) * SEQ + tt] = pk;
        } else {
          unsigned short* dst = (c == 0) ? out0 : out1;
          float sc = (c == 0) ? QSCALE : 1.0f;
#pragma unroll
          for (int r = 0; r < 4; r++)
            dst[(((size_t)(b * NH + h) * SEQ + tt + r) << 6) + dd] =
                f2bf(acc[mt][nt][r] * sc);
        }
      }
    }
}

// ---------------------------------------------------------------------------
// Flash attention. Q,K: [bh][T][64] bf16 (Q pre-scaled); Vt: [bh][64][T] bf16.
// Block = 256 thr = 4 waves; wave owns 32 q-rows (block 128); 64-key tiles.
// S^T = K·Q^T via 32x32x16 MFMA -> 4 consecutive keys per lane -> packed b64
// P spills. Max-free deferred softmax (raw v_exp_f32, fast RNE pack).
// K/Vt staged by global_load_lds with granule-XOR swizzle (no VALU staging).
// ---------------------------------------------------------------------------
__global__ __launch_bounds__(256) void attn_kernel(
    const unsigned short* __restrict__ Q, const unsigned short* __restrict__ K,
    const unsigned short* __restrict__ Vt, unsigned short* __restrict__ ctx) {
  __shared__ unsigned short KsL[64 * 64];   // granule-swizzled [key][d]
  __shared__ unsigned short VtL[64 * 64];   // granule-swizzled [d][key]
  __shared__ unsigned short Ps[4][32][72];  // per-wave P[qrow][key]
  __shared__ float lbuf[4][32];             // 1/l per q-row

  const int tid = threadIdx.x;
  const int wave = tid >> 6;
  const int lane = tid & 63;
  const int half = lane >> 5;
  const int l31 = lane & 31;
  const int bh = blockIdx.y;
  const int q0 = blockIdx.x * 128 + wave * 32;
  const size_t kqbase = (size_t)bh * SEQ * DH;
  const size_t vbase = (size_t)bh * DH * SEQ;

  // Q B-fragments (n=qrow=l31, k=d): 4 d-chunks of 16.
  short8 bQ[4];
#pragma unroll
  for (int dc = 0; dc < 4; dc++)
    bQ[dc] = *(const short8*)&Q[kqbase + (size_t)(q0 + l31) * DH + dc * 16 + half * 8];

  f32x16 o[2];
#pragma unroll
  for (int nb = 0; nb < 2; nb++)
#pragma unroll
    for (int j = 0; j < 16; j++) o[nb][j] = 0.f;
  float l_part = 0.f;

  const int xsw = l31 & 7;  // bank-swizzle key for this lane's fragment rows

  for (int kt = 0; kt < SEQ / 64; kt++) {
    const size_t kg = kqbase + (size_t)kt * 64 * DH;
    const size_t vg = vbase + (size_t)kt * 64;
    // Stage K (64key x 64d) and Vt (64d x 64key): 16B granules, XOR-swizzled.
#pragma unroll
    for (int it = 0; it < 2; it++) {
      int g = wave * 128 + it * 64 + lane;  // granule id 0..511
      int row = g >> 3;                     // key (K) / d (Vt)
      int goff = ((g & 7) ^ (row & 7)) * 8; // swizzled source offset
      gload_lds16(&K[kg + (size_t)row * DH + goff],
                  &KsL[(size_t)(wave * 128 + it * 64) * 8]);
      gload_lds16(&Vt[vg + (size_t)row * SEQ + goff],
                  &VtL[(size_t)(wave * 128 + it * 64) * 8]);
    }
    __syncthreads();

    // S^T = K·Q^T : two 32-key blocks, contraction d=64 (4 chained MFMA).
#pragma unroll
    for (int kb = 0; kb < 2; kb++) {
      f32x16 s;
#pragma unroll
      for (int j = 0; j < 16; j++) s[j] = 0.f;
#pragma unroll
      for (int dc = 0; dc < 4; dc++) {
        const short8 aK = *(const short8*)&KsL[(size_t)(kb * 32 + l31) * 64 +
                                               ((dc * 2 + half) ^ xsw) * 8];
        s = __builtin_amdgcn_mfma_f32_32x32x16_bf16(aK, bQ[dc], s, 0, 0, 0);
      }
      // p = exp2(s) (raw v_exp_f32); pack 4 consecutive keys per b64 write.
#pragma unroll
      for (int gq = 0; gq < 4; gq++) {
        float p0 = __builtin_amdgcn_exp2f(s[gq * 4 + 0]);
        float p1 = __builtin_amdgcn_exp2f(s[gq * 4 + 1]);
        float p2 = __builtin_amdgcn_exp2f(s[gq * 4 + 2]);
        float p3 = __builtin_amdgcn_exp2f(s[gq * 4 + 3]);
        l_part += (p0 + p1) + (p2 + p3);
        uint2v pk;
        pk[0] = pack2bf(p0, p1);
        pk[1] = pack2bf(p2, p3);
        *(uint2v*)&Ps[wave][l31][kb * 32 + gq * 8 + half * 4] = pk;
      }
    }

    // O += P·V : contraction key=64 (4 chunks of 16), 2 d-blocks of 32.
#pragma unroll
    for (int kc = 0; kc < 4; kc++) {
      const short8 pA = *(const short8*)&Ps[wave][l31][kc * 16 + half * 8];
#pragma unroll
      for (int nb = 0; nb < 2; nb++) {
        const short8 bV = *(const short8*)&VtL[(size_t)(nb * 32 + l31) * 64 +
                                               ((kc * 2 + half) ^ xsw) * 8];
        o[nb] = __builtin_amdgcn_mfma_f32_32x32x16_bf16(pA, bV, o[nb], 0, 0, 0);
      }
    }
    __syncthreads();
  }

  // l: both halves hold partial sums for qrow=l31 -> combine; store 1/l.
  l_part += __shfl_xor(l_part, 32);
  lbuf[wave][l31] = 1.0f / l_part;
  __syncthreads();

  const int b = bh >> 4;
  const int h = bh & 15;
#pragma unroll
  for (int gq = 0; gq < 4; gq++)
#pragma unroll
    for (int j = 0; j < 4; j++) {
      int ql = j + gq * 8 + half * 4;  // q within wave (C-layout row)
      float inv = lbuf[wave][ql];
      int token = blockIdx.x * 128 + wave * 32 + ql;
#pragma unroll
      for (int nb = 0; nb < 2; nb++)
        ctx[((size_t)b * SEQ + token) * DM + h * DH + nb * 32 + l31] =
            f2bf(o[nb][gq * 4 + j] * inv);
    }
}

extern "C" void kernel_launch(void* const* d_in, const int* in_sizes, int n_in,
                              void* d_out, int out_size, void* d_ws,
                              size_t ws_size, hipStream_t stream) {
  const float* x = (const float*)d_in[0];     // [8192,1024] fp32
  const float* Wqkv = (const float*)d_in[1];  // [1024,3072] fp32
  const float* Wo = (const float*)d_in[2];    // [1024,1024] fp32
  float* out = (float*)d_out;                 // [8192,1024] fp32
  unsigned short* ws = (unsigned short*)d_ws;

  unsigned short* Qb = ws;                          // [bh][T][64], pre-scaled
  unsigned short* Kb = ws + SEG;                    // [bh][T][64]
  unsigned short* Vt = ws + 2 * SEG;                // [bh][64][T]
  unsigned short* Ctx = ws + 3 * SEG;               // [8192][1024]
  unsigned short* WqT = Ctx + (size_t)MTOK * DM;    // [3072][1024]
  unsigned short* WoT = WqT + (size_t)3 * DM * DM;  // [1024][1024]
  unsigned short* Xb = WoT + (size_t)DM * DM;       // [8192][1024]
  const size_t need =
      ((size_t)(Xb - ws) + (size_t)MTOK * DM) * sizeof(unsigned short);

  transpose_w<<<dim3(3 * DM / 64, DM / 64), 256, 0, stream>>>(Wqkv, WqT, DM, 3 * DM);
  transpose_w<<<dim3(DM / 64, DM / 64), 256, 0, stream>>>(Wo, WoT, DM, DM);

  if (ws_size >= need) {
    xcast<<<(MTOK * DM) / (256 * 8), 256, 0, stream>>>(x, Xb);
    gemm_kernel<2><<<dim3(3 * DM / 128, MTOK / 128), 256, 0, stream>>>(
        (const void*)Xb, WqT, Qb, Kb, Vt, nullptr, MTOK, 3 * DM, DM);
  } else {
    gemm_kernel<0><<<dim3(3 * DM / 128, MTOK / 128), 256, 0, stream>>>(
        (const void*)x, WqT, Qb, Kb, Vt, nullptr, MTOK, 3 * DM, DM);
  }
  attn_kernel<<<dim3(SEQ / 128, NBATCH * NH), 256, 0, stream>>>(Qb, Kb, Vt, Ctx);
  gemm_kernel<1><<<dim3(DM / 128, MTOK / 128), 256, 0, stream>>>(
      (const void*)Ctx, WoT, nullptr, nullptr, nullptr, out, MTOK, DM, DM);
}

// Round 7
// 276.853 us; speedup vs baseline: 3.7623x; 1.0758x over previous
//
#include <hip/hip_runtime.h>
#include <hip/hip_bf16.h>

typedef __attribute__((ext_vector_type(8))) short short8;
typedef __attribute__((ext_vector_type(4))) float f32x4;
typedef __attribute__((ext_vector_type(16))) float f32x16;
typedef __attribute__((ext_vector_type(2))) unsigned int uint2v;
typedef __attribute__((ext_vector_type(4))) unsigned int uint4v;

#define SEQ    2048
#define DM     1024
#define NH     16
#define DH     64
#define NBATCH 4
#define MTOK   (NBATCH * SEQ)                       // 8192 tokens
#define SEG    ((size_t)NBATCH * NH * SEQ * DH)     // 8388608 elems per Q/K/V buffer
// Q pre-scaled by 1/sqrt(64) * log2(e) so attention inner loop is exp2 only.
#define QSCALE 0.18033688f

// Fast RNE float->bf16 for FINITE values: bf16 bits land in the high 16.
static __device__ __forceinline__ unsigned bfbits(float f) {
  unsigned u = __float_as_uint(f);
  return u + 0x7fffu + ((u >> 16) & 1u);
}
static __device__ __forceinline__ unsigned short f2bf(float f) {
  return (unsigned short)(bfbits(f) >> 16);
}
// RNE pack of two floats to packed bf16x2 (lo in low half).
static __device__ __forceinline__ unsigned pack2bf(float lo, float hi) {
  return __builtin_amdgcn_perm(bfbits(hi), bfbits(lo), 0x07060302u);
}
// Truncation pack (round-toward-zero for positives): 1 v_perm on raw bits.
static __device__ __forceinline__ unsigned pack2tr(unsigned ulo, unsigned uhi) {
  return __builtin_amdgcn_perm(uhi, ulo, 0x07060302u);
}

typedef const __attribute__((address_space(1))) unsigned int* gp_t;
typedef __attribute__((address_space(3))) unsigned int* lp_t;
static __device__ __forceinline__ void gload_lds16(const void* g, void* l) {
  __builtin_amdgcn_global_load_lds((gp_t)g, (lp_t)l, 16, 0, 0);
}

// ---------------------------------------------------------------------------
// x fp32 -> bf16 cast (8 elems/thread).
// ---------------------------------------------------------------------------
__global__ __launch_bounds__(256) void xcast(const float* __restrict__ x,
                                             unsigned short* __restrict__ xb) {
  size_t i = ((size_t)blockIdx.x * 256 + threadIdx.x) * 8;
  f32x4 a = *(const f32x4*)&x[i];
  f32x4 b = *(const f32x4*)&x[i + 4];
  uint4v s;
  s[0] = pack2bf(a[0], a[1]);
  s[1] = pack2bf(a[2], a[3]);
  s[2] = pack2bf(b[0], b[1]);
  s[3] = pack2bf(b[2], b[3]);
  *(uint4v*)&xb[i] = s;
}

// ---------------------------------------------------------------------------
// Weight transpose: W [K][N] fp32 -> WT [N][K] bf16. 64x64 tiles, 256 thr.
// ---------------------------------------------------------------------------
__global__ __launch_bounds__(256) void transpose_w(
    const float* __restrict__ W, unsigned short* __restrict__ WT, int K, int N) {
  __shared__ float T[64][65];
  const int tid = threadIdx.x;
  const int n0 = blockIdx.x * 64;
  const int k0 = blockIdx.y * 64;
#pragma unroll
  for (int it = 0; it < 4; it++) {
    int row = it * 16 + (tid >> 4);
    int c4 = (tid & 15) * 4;
    f32x4 v = *(const f32x4*)&W[(size_t)(k0 + row) * N + n0 + c4];
#pragma unroll
    for (int j = 0; j < 4; j++) T[row][c4 + j] = v[j];
  }
  __syncthreads();
#pragma unroll
  for (int it = 0; it < 2; it++) {
    int chunk = tid + it * 256;
    int n = chunk >> 3;
    int c8 = (chunk & 7) * 8;
    uint4v s;
#pragma unroll
    for (int j = 0; j < 4; j++)
      s[j] = pack2bf(T[c8 + 2 * j][n], T[c8 + 2 * j + 1][n]);
    *(uint4v*)&WT[(size_t)(n0 + n) * K + k0 + c8] = s;
  }
}

// ---------------------------------------------------------------------------
// GEMM: C[M,N] = A[M,K] @ BT[N,K]^T, fp32 accum. 128x128 tile, BK=64,
// 256 threads (4 waves 2x2). Tiles stored with granule-XOR swizzle:
// LDS[r][g] holds global granule (g ^ (r&7)) of row r (granule = 8 shorts).
// -> conflict-free b128 fragment reads; DMA staging swizzles the SOURCE.
// MODE 0: A fp32 (VALU cvt staging); QKV scatter epilogue (V transposed).
// MODE 2: A bf16 (DMA staging);      QKV scatter epilogue (V transposed).
// MODE 1: A bf16 (DMA staging);      fp32 row-major output.
// ---------------------------------------------------------------------------
template <int MODE>
__global__ __launch_bounds__(256) void gemm_kernel(
    const void* __restrict__ Av, const unsigned short* __restrict__ BT,
    unsigned short* __restrict__ out0, unsigned short* __restrict__ out1,
    unsigned short* __restrict__ out2, float* __restrict__ outf,
    int M, int N, int K) {
  __shared__ unsigned short As[128][64];
  __shared__ unsigned short Bs[128][64];

  const int tid = threadIdx.x;
  const int wave = tid >> 6;
  const int lane = tid & 63;
  const int quad = lane >> 4;
  const int lc = lane & 15;
  const int wr = wave >> 1;
  const int wc = wave & 1;
  const int m0 = blockIdx.y * 128;
  const int n0 = blockIdx.x * 128;
  const int xsw = lc & 7;               // fragment-read swizzle key
  const int lr8 = lane >> 3;            // staging: row within 8-row group
  const int sgo = ((lane & 7) ^ (lr8 & 7)) * 8;  // swizzled source offset

  f32x4 acc[4][4];
#pragma unroll
  for (int i = 0; i < 4; i++)
#pragma unroll
    for (int j = 0; j < 4; j++) acc[i][j] = (f32x4){0.f, 0.f, 0.f, 0.f};

  for (int k0 = 0; k0 < K; k0 += 64) {
    // ---- Stage A tile (128 x 64) ----
    if (MODE == 0) {
      const float* A = (const float*)Av;
#pragma unroll
      for (int i = 0; i < 4; i++) {
        int chunk = tid + i * 256;      // 1024 granules
        int r = chunk >> 3;
        int g = chunk & 7;
        int scol = (g ^ (r & 7)) * 8;
        f32x4 v0 = *(const f32x4*)&A[(size_t)(m0 + r) * K + k0 + scol];
        f32x4 v1 = *(const f32x4*)&A[(size_t)(m0 + r) * K + k0 + scol + 4];
        uint4v s;
        s[0] = pack2bf(v0[0], v0[1]);
        s[1] = pack2bf(v0[2], v0[3]);
        s[2] = pack2bf(v1[0], v1[1]);
        s[3] = pack2bf(v1[2], v1[3]);
        *(uint4v*)&As[r][g * 8] = s;
      }
    } else {
      const unsigned short* A = (const unsigned short*)Av;
#pragma unroll
      for (int it = 0; it < 4; it++) {
        int rbase = wave * 32 + it * 8;  // 8 rows = 1 KB per instruction
        gload_lds16(&A[(size_t)(m0 + rbase + lr8) * K + k0 + sgo],
                    &As[rbase][0]);
      }
    }
    // ---- Stage B tile (128 n-rows x 64 k) ----
#pragma unroll
    for (int it = 0; it < 4; it++) {
      int rbase = wave * 32 + it * 8;
      gload_lds16(&BT[(size_t)(n0 + rbase + lr8) * K + k0 + sgo],
                  &Bs[rbase][0]);
    }
    __syncthreads();

#pragma unroll
    for (int kc = 0; kc < 2; kc++) {
      short8 aA[4], bB[4];
#pragma unroll
      for (int mt = 0; mt < 4; mt++)
        aA[mt] = *(const short8*)&As[wr * 64 + mt * 16 + lc]
                                    [((kc * 4 + quad) ^ xsw) * 8];
#pragma unroll
      for (int nt = 0; nt < 4; nt++)
        bB[nt] = *(const short8*)&Bs[wc * 64 + nt * 16 + lc]
                                    [((kc * 4 + quad) ^ xsw) * 8];
#pragma unroll
      for (int mt = 0; mt < 4; mt++)
#pragma unroll
        for (int nt = 0; nt < 4; nt++)
          acc[mt][nt] = __builtin_amdgcn_mfma_f32_16x16x32_bf16(
              aA[mt], bB[nt], acc[mt][nt], 0, 0, 0);
    }
    __syncthreads();
  }

  // Epilogue: C/D layout col=lane&15, row=quad*4+reg.
  const int c = n0 >> 10;  // QKV segment (block-uniform): 0=Q 1=K 2=V
#pragma unroll
  for (int mt = 0; mt < 4; mt++)
#pragma unroll
    for (int nt = 0; nt < 4; nt++) {
      int rb = m0 + wr * 64 + mt * 16 + quad * 4;  // 4 consecutive tokens
      int col = n0 + wc * 64 + nt * 16 + lc;
      if (MODE == 1) {
#pragma unroll
        for (int r = 0; r < 4; r++)
          outf[(size_t)(rb + r) * N + col] = acc[mt][nt][r];
      } else {
        int rem = col & 1023;
        int h = rem >> 6;
        int dd = rem & 63;
        int b = rb >> 11;
        int tt = rb & 2047;
        if (c == 2) {
          uint2v pk;
          pk[0] = pack2bf(acc[mt][nt][0], acc[mt][nt][1]);
          pk[1] = pack2bf(acc[mt][nt][2], acc[mt][nt][3]);
          *(uint2v*)&out2[(((size_t)(b * NH + h)) * DH + dd) * SEQ + tt] = pk;
        } else {
          unsigned short* dst = (c == 0) ? out0 : out1;
          float sc = (c == 0) ? QSCALE : 1.0f;
#pragma unroll
          for (int r = 0; r < 4; r++)
            dst[(((size_t)(b * NH + h) * SEQ + tt + r) << 6) + dd] =
                f2bf(acc[mt][nt][r] * sc);
        }
      }
    }
}

// ---------------------------------------------------------------------------
// Flash attention. Q,K: [bh][T][64] bf16 (Q pre-scaled); Vt: [bh][64][T] bf16.
// Block = 256 thr = 4 waves; wave owns 32 q-rows (block 128); 64-key tiles.
// S^T = K·Q^T via 32x32x16 MFMA -> 4 consecutive keys per lane. P packed by
// TRUNCATION (1 v_perm / pair); l accumulates the SAME truncated values so
// normalization is self-consistent. Ps stride 68 shorts (34 dwords, ~2-way).
// K/Vt staged by global_load_lds with granule-XOR swizzle (no VALU staging).
// ---------------------------------------------------------------------------
__global__ __launch_bounds__(256) void attn_kernel(
    const unsigned short* __restrict__ Q, const unsigned short* __restrict__ K,
    const unsigned short* __restrict__ Vt, unsigned short* __restrict__ ctx) {
  __shared__ unsigned short KsL[64 * 64];   // granule-swizzled [key][d]
  __shared__ unsigned short VtL[64 * 64];   // granule-swizzled [d][key]
  __shared__ unsigned short Ps[4][32][68];  // per-wave P[qrow][key]
  __shared__ float lbuf[4][32];             // 1/l per q-row

  const int tid = threadIdx.x;
  const int wave = tid >> 6;
  const int lane = tid & 63;
  const int half = lane >> 5;
  const int l31 = lane & 31;
  const int bh = blockIdx.y;
  const int q0 = blockIdx.x * 128 + wave * 32;
  const size_t kqbase = (size_t)bh * SEQ * DH;
  const size_t vbase = (size_t)bh * DH * SEQ;

  // Q B-fragments (n=qrow=l31, k=d): 4 d-chunks of 16.
  short8 bQ[4];
#pragma unroll
  for (int dc = 0; dc < 4; dc++)
    bQ[dc] = *(const short8*)&Q[kqbase + (size_t)(q0 + l31) * DH + dc * 16 + half * 8];

  f32x16 o[2];
#pragma unroll
  for (int nb = 0; nb < 2; nb++)
#pragma unroll
    for (int j = 0; j < 16; j++) o[nb][j] = 0.f;
  float l_part = 0.f;

  const int xsw = l31 & 7;  // bank-swizzle key for this lane's fragment rows
  // Hoisted staging geometry (granule id = wave*128 + it*64 + lane).
  const int g0 = wave * 128 + lane;
  const int r0 = g0 >> 3, r1 = (g0 + 64) >> 3;
  const size_t so0 = (size_t)r0 * DH + (((g0 & 7) ^ (r0 & 7)) * 8);
  const size_t so1 = (size_t)r1 * DH + (((g0 & 7) ^ (r1 & 7)) * 8);
  const size_t sv0 = (size_t)r0 * SEQ + (((g0 & 7) ^ (r0 & 7)) * 8);
  const size_t sv1 = (size_t)r1 * SEQ + (((g0 & 7) ^ (r1 & 7)) * 8);
  unsigned short* ksl0 = &KsL[(size_t)(wave * 128) * 8];
  unsigned short* ksl1 = &KsL[(size_t)(wave * 128 + 64) * 8];
  unsigned short* vtl0 = &VtL[(size_t)(wave * 128) * 8];
  unsigned short* vtl1 = &VtL[(size_t)(wave * 128 + 64) * 8];

  for (int kt = 0; kt < SEQ / 64; kt++) {
    const size_t kg = kqbase + (size_t)kt * 64 * DH;
    const size_t vg = vbase + (size_t)kt * 64;
    gload_lds16(&K[kg + so0], ksl0);
    gload_lds16(&K[kg + so1], ksl1);
    gload_lds16(&Vt[vg + sv0], vtl0);
    gload_lds16(&Vt[vg + sv1], vtl1);
    __syncthreads();

    // S^T = K·Q^T : two 32-key blocks, contraction d=64 (4 chained MFMA).
#pragma unroll
    for (int kb = 0; kb < 2; kb++) {
      f32x16 s;
#pragma unroll
      for (int j = 0; j < 16; j++) s[j] = 0.f;
#pragma unroll
      for (int dc = 0; dc < 4; dc++) {
        const short8 aK = *(const short8*)&KsL[(size_t)(kb * 32 + l31) * 64 +
                                               ((dc * 2 + half) ^ xsw) * 8];
        s = __builtin_amdgcn_mfma_f32_32x32x16_bf16(aK, bQ[dc], s, 0, 0, 0);
      }
      // p = exp2(s); truncate to bf16; l sums the truncated values.
#pragma unroll
      for (int gq = 0; gq < 4; gq++) {
        unsigned u0 = __float_as_uint(__builtin_amdgcn_exp2f(s[gq * 4 + 0]));
        unsigned u1 = __float_as_uint(__builtin_amdgcn_exp2f(s[gq * 4 + 1]));
        unsigned u2 = __float_as_uint(__builtin_amdgcn_exp2f(s[gq * 4 + 2]));
        unsigned u3 = __float_as_uint(__builtin_amdgcn_exp2f(s[gq * 4 + 3]));
        float t0 = __uint_as_float(u0 & 0xffff0000u);
        float t1 = __uint_as_float(u1 & 0xffff0000u);
        float t2 = __uint_as_float(u2 & 0xffff0000u);
        float t3 = __uint_as_float(u3 & 0xffff0000u);
        l_part += (t0 + t1) + (t2 + t3);
        uint2v pk;
        pk[0] = pack2tr(u0, u1);
        pk[1] = pack2tr(u2, u3);
        *(uint2v*)&Ps[wave][l31][kb * 32 + gq * 8 + half * 4] = pk;
      }
    }

    // O += P·V : contraction key=64 (4 chunks of 16), 2 d-blocks of 32.
#pragma unroll
    for (int kc = 0; kc < 4; kc++) {
      uint2v plo = *(const uint2v*)&Ps[wave][l31][kc * 16 + half * 8];
      uint2v phi = *(const uint2v*)&Ps[wave][l31][kc * 16 + half * 8 + 4];
      union { unsigned u[4]; short8 s8; } cv;
      cv.u[0] = plo[0]; cv.u[1] = plo[1]; cv.u[2] = phi[0]; cv.u[3] = phi[1];
      const short8 pA = cv.s8;
#pragma unroll
      for (int nb = 0; nb < 2; nb++) {
        const short8 bV = *(const short8*)&VtL[(size_t)(nb * 32 + l31) * 64 +
                                               ((kc * 2 + half) ^ xsw) * 8];
        o[nb] = __builtin_amdgcn_mfma_f32_32x32x16_bf16(pA, bV, o[nb], 0, 0, 0);
      }
    }
    __syncthreads();
  }

  // l: both halves hold partial sums for qrow=l31 -> combine; store 1/l.
  l_part += __shfl_xor(l_part, 32);
  lbuf[wave][l31] = 1.0f / l_part;
  __syncthreads();

  const int b = bh >> 4;
  const int h = bh & 15;
#pragma unroll
  for (int gq = 0; gq < 4; gq++)
#pragma unroll
    for (int j = 0; j < 4; j++) {
      int ql = j + gq * 8 + half * 4;  // q within wave (C-layout row)
      float inv = lbuf[wave][ql];
      int token = blockIdx.x * 128 + wave * 32 + ql;
#pragma unroll
      for (int nb = 0; nb < 2; nb++)
        ctx[((size_t)b * SEQ + token) * DM + h * DH + nb * 32 + l31] =
            f2bf(o[nb][gq * 4 + j] * inv);
    }
}

extern "C" void kernel_launch(void* const* d_in, const int* in_sizes, int n_in,
                              void* d_out, int out_size, void* d_ws,
                              size_t ws_size, hipStream_t stream) {
  const float* x = (const float*)d_in[0];     // [8192,1024] fp32
  const float* Wqkv = (const float*)d_in[1];  // [1024,3072] fp32
  const float* Wo = (const float*)d_in[2];    // [1024,1024] fp32
  float* out = (float*)d_out;                 // [8192,1024] fp32
  unsigned short* ws = (unsigned short*)d_ws;

  unsigned short* Qb = ws;                          // [bh][T][64], pre-scaled
  unsigned short* Kb = ws + SEG;                    // [bh][T][64]
  unsigned short* Vt = ws + 2 * SEG;                // [bh][64][T]
  unsigned short* Ctx = ws + 3 * SEG;               // [8192][1024]
  unsigned short* WqT = Ctx + (size_t)MTOK * DM;    // [3072][1024]
  unsigned short* WoT = WqT + (size_t)3 * DM * DM;  // [1024][1024]
  unsigned short* Xb = WoT + (size_t)DM * DM;       // [8192][1024]
  const size_t need =
      ((size_t)(Xb - ws) + (size_t)MTOK * DM) * sizeof(unsigned short);

  transpose_w<<<dim3(3 * DM / 64, DM / 64), 256, 0, stream>>>(Wqkv, WqT, DM, 3 * DM);
  transpose_w<<<dim3(DM / 64, DM / 64), 256, 0, stream>>>(Wo, WoT, DM, DM);

  if (ws_size >= need) {
    xcast<<<(MTOK * DM) / (256 * 8), 256, 0, stream>>>(x, Xb);
    gemm_kernel<2><<<dim3(3 * DM / 128, MTOK / 128), 256, 0, stream>>>(
        (const void*)Xb, WqT, Qb, Kb, Vt, nullptr, MTOK, 3 * DM, DM);
  } else {
    gemm_kernel<0><<<dim3(3 * DM / 128, MTOK / 128), 256, 0, stream>>>(
        (const void*)x, WqT, Qb, Kb, Vt, nullptr, MTOK, 3 * DM, DM);
  }
  attn_kernel<<<dim3(SEQ / 128, NBATCH * NH), 256, 0, stream>>>(Qb, Kb, Vt, Ctx);
  gemm_kernel<1><<<dim3(DM / 128, MTOK / 128), 256, 0, stream>>>(
      (const void*)Ctx, WoT, nullptr, nullptr, nullptr, out, MTOK, DM, DM);
}